// Round 13
// baseline (202.991 us; speedup 1.0000x reference)
//
#include <hip/hip_runtime.h>
#include <hip/hip_bf16.h>

// SNN: B=2048, NI=1024, NH=2048, NO=10, T=128, BETA=0.95, THR=1.0
// K1: cur1 = x @ w1^T + b1 via bf16x3 MFMA.
// K2: chunked LIF + time-as-M MFMA; GB=4, batch split across 2 waves.
// r13: drop stag (merge P3'/P4) -> LDS 74368; 2 blocks/CU needs 148.7KB,
// leaving 15KB headroom vs r12's 864B (suspected runtime LDS reserve
// blocked co-residency at 2x79488=158976 of 163840).

#define B_   2048
#define NI_  1024
#define NH_  2048
#define NO_  10
#define T_   128
#define GB_  4
#define NBLK (B_ / GB_)   // 512 blocks
#define TC_  32
#define NCH  (T_ / TC_)

typedef __attribute__((ext_vector_type(8))) short short8;
typedef __attribute__((ext_vector_type(4))) float f32x4;
typedef __attribute__((ext_vector_type(4))) unsigned int u32x4;

// bf16 round-to-nearest-even of an f32, low 16 bits.
__device__ __forceinline__ unsigned int bf16_rne(float f) {
  unsigned int u = __float_as_uint(f);
  return (u + 0x7FFFu + ((u >> 16) & 1u)) >> 16;
}

// ---------------- Kernel 1: cur1 = x @ w1^T + b1 (bf16x3 MFMA) --------------
#define G_ASTRIDE 144
#define G_AOFF    0
#define G_BOFF    (128 * G_ASTRIDE)
#define G_SMEM    (2 * 128 * G_ASTRIDE)

__global__ __launch_bounds__(512, 2) void gemm_cur1(
    const float* __restrict__ x, const float* __restrict__ w1,
    const float* __restrict__ b1, float* __restrict__ cur1) {
  __shared__ __align__(16) char smem[G_SMEM];
  const int tid = threadIdx.x;
  const int lane = tid & 63;
  const int wv = tid >> 6;
  const int wm = wv >> 2;
  const int wn = wv & 3;
  const int n15 = lane & 15;
  const int g = lane >> 4;
  const int brow = blockIdx.y * 128;
  const int bcol = blockIdx.x * 128;

  const int r_st = tid >> 3;
  const int kq = tid & 7;

  f32x4 acc[4][2];
#pragma unroll
  for (int tm = 0; tm < 4; ++tm)
#pragma unroll
    for (int tn = 0; tn < 2; ++tn) acc[tm][tn] = f32x4{0, 0, 0, 0};

  for (int kt = 0; kt < NI_; kt += 32) {
#pragma unroll
    for (int p = 0; p < 2; ++p) {
      const int r = r_st + p * 64;
      const float4 va = *reinterpret_cast<const float4*>(
          &x[(size_t)(brow + r) * NI_ + kt + kq * 4]);
      const float4 vb = *reinterpret_cast<const float4*>(
          &w1[(size_t)(bcol + r) * NI_ + kt + kq * 4]);
      const float fa[4] = {va.x, va.y, va.z, va.w};
      const float fb[4] = {vb.x, vb.y, vb.z, vb.w};
      unsigned ha[4], la[4], hb[4], lb[4];
#pragma unroll
      for (int c = 0; c < 4; ++c) {
        ha[c] = bf16_rne(fa[c]);
        la[c] = bf16_rne(fa[c] - __uint_as_float(ha[c] << 16));
        hb[c] = bf16_rne(fb[c]);
        lb[c] = bf16_rne(fb[c] - __uint_as_float(hb[c] << 16));
      }
      char* arow = smem + G_AOFF + r * G_ASTRIDE;
      char* brw  = smem + G_BOFF + r * G_ASTRIDE;
      *reinterpret_cast<uint2*>(arow + kq * 8) =
          uint2{ha[0] | (ha[1] << 16), ha[2] | (ha[3] << 16)};
      *reinterpret_cast<uint2*>(arow + 64 + kq * 8) =
          uint2{la[0] | (la[1] << 16), la[2] | (la[3] << 16)};
      *reinterpret_cast<uint2*>(brw + kq * 8) =
          uint2{hb[0] | (hb[1] << 16), hb[2] | (hb[3] << 16)};
      *reinterpret_cast<uint2*>(brw + 64 + kq * 8) =
          uint2{lb[0] | (lb[1] << 16), lb[2] | (lb[3] << 16)};
    }
    __syncthreads();

    short8 ah[4], al[4], bh2[2], bl2[2];
#pragma unroll
    for (int tm = 0; tm < 4; ++tm) {
      const char* p = smem + G_AOFF + (wm * 64 + tm * 16 + n15) * G_ASTRIDE;
      ah[tm] = *reinterpret_cast<const short8*>(p + g * 16);
      al[tm] = *reinterpret_cast<const short8*>(p + 64 + g * 16);
    }
#pragma unroll
    for (int tn = 0; tn < 2; ++tn) {
      const char* p = smem + G_BOFF + (wn * 32 + tn * 16 + n15) * G_ASTRIDE;
      bh2[tn] = *reinterpret_cast<const short8*>(p + g * 16);
      bl2[tn] = *reinterpret_cast<const short8*>(p + 64 + g * 16);
    }
#pragma unroll
    for (int tm = 0; tm < 4; ++tm)
#pragma unroll
      for (int tn = 0; tn < 2; ++tn) {
        acc[tm][tn] = __builtin_amdgcn_mfma_f32_16x16x32_bf16(
            ah[tm], bh2[tn], acc[tm][tn], 0, 0, 0);
        acc[tm][tn] = __builtin_amdgcn_mfma_f32_16x16x32_bf16(
            ah[tm], bl2[tn], acc[tm][tn], 0, 0, 0);
        acc[tm][tn] = __builtin_amdgcn_mfma_f32_16x16x32_bf16(
            al[tm], bh2[tn], acc[tm][tn], 0, 0, 0);
      }
    __syncthreads();
  }

#pragma unroll
  for (int tn = 0; tn < 2; ++tn) {
    const int col = bcol + wn * 32 + tn * 16 + n15;
    const float bias = b1[col];
#pragma unroll
    for (int tm = 0; tm < 4; ++tm) {
      const int rowb = brow + wm * 64 + tm * 16 + g * 4;
#pragma unroll
      for (int r = 0; r < 4; ++r)
        cur1[(size_t)(rowb + r) * NH_ + col] = acc[tm][tn][r] + bias;
    }
  }
}

// ---------------- Kernel 2: chunked LIF + time-as-M MFMA --------------------
// 8 waves: hf = w>>2 (neuron half), bq = w&3 (batch). Lane owns 16 neurons
// h = hf*1024 + lane*16 + i. Bits word k = h/32 = hf*32 + (lane>>1),
// halfword (lane&1).
// LDS map (bytes):
//   bits u32[4 b][32 tl][65]            at 0      (33280)
//   lut  uint2[16]                      at 33280  (128)
//   comb f32[8 w][4 b][2][4][10][4]     at 33408  (40960)
#define BITS_OFF 0
#define LUT_OFF  33280
#define COMB_OFF 33408
#define SMEM_BYTES 74368

__global__ __launch_bounds__(512, 2) void snn_loop(
    const float* __restrict__ cur1, const float* __restrict__ w2,
    const float* __restrict__ b2, float* __restrict__ spk2_rec,
    float* __restrict__ mem2_rec) {
  extern __shared__ char smem[];
  uint2* lutw = reinterpret_cast<uint2*>(smem + LUT_OFF);
  const uint2* lut = lutw;
  float* comb = reinterpret_cast<float*>(smem + COMB_OFF);
  const int tid = threadIdx.x;
  const int lane = tid & 63;
  const int w = tid >> 6;
  const int hf = w >> 2;               // neuron half
  const int bq = w & 3;                // local batch
  const int bbase = blockIdx.x * GB_;
  const int bb = bbase + bq;

  if (tid < 16) {
    lutw[tid] = uint2{(tid & 1 ? 0x3F80u : 0u) | (tid & 2 ? 0x3F800000u : 0u),
                      (tid & 4 ? 0x3F80u : 0u) | (tid & 8 ? 0x3F800000u : 0u)};
  }

  // ---- layer-1 state: 16 contiguous h per lane ----
  float mem1[16], c1v[16], spk[16];
  {
    const float* base = cur1 + (size_t)bb * NH_ + hf * 1024 + lane * 16;
#pragma unroll
    for (int q = 0; q < 4; ++q) {
      const float4 v = *reinterpret_cast<const float4*>(base + q * 4);
      c1v[q * 4 + 0] = v.x; c1v[q * 4 + 1] = v.y;
      c1v[q * 4 + 2] = v.z; c1v[q * 4 + 3] = v.w;
    }
#pragma unroll
    for (int i = 0; i < 16; ++i) { mem1[i] = 0.0f; spk[i] = 0.0f; }
  }

  // ---- w2 B-fragments in registers (hi/lo split) — verified ----
  u32x4 bhi[8], blo[8];
  {
    const int o = lane & 15;
    const int koff = (lane >> 4) * 8;
#pragma unroll
    for (int kbl = 0; kbl < 8; ++kbl) {
      const int kb = w * 8 + kbl;
      unsigned int hw[4], lw[4];
#pragma unroll
      for (int p = 0; p < 4; ++p) {
        unsigned int h0 = 0, h1 = 0, l0 = 0, l1 = 0;
        if (o < NO_) {
          const int k = kb * 32 + koff + p * 2;
          const float f0 = w2[(size_t)o * NH_ + k];
          const float f1 = w2[(size_t)o * NH_ + k + 1];
          h0 = bf16_rne(f0);
          h1 = bf16_rne(f1);
          l0 = bf16_rne(f0 - __uint_as_float(h0 << 16));
          l1 = bf16_rne(f1 - __uint_as_float(h1 << 16));
        }
        hw[p] = h0 | (h1 << 16);
        lw[p] = l0 | (l1 << 16);
      }
      bhi[kbl] = u32x4{hw[0], hw[1], hw[2], hw[3]};
      blo[kbl] = u32x4{lw[0], lw[1], lw[2], lw[3]};
    }
  }

  // ---- layer-2 state: wave bq (hf==0), lanes < NO_ ----
  float mem2 = 0.0f, spk2 = 0.0f, b2v = 0.0f;
  float *srec = nullptr, *mrec = nullptr;
  if (hf == 0 && lane < NO_) {
    b2v = b2[lane];
    srec = spk2_rec + (size_t)bb * NO_ + lane;
    mrec = mem2_rec + (size_t)bb * NO_ + lane;
  }

  const int n15 = lane & 15;
  const int g = lane >> 4;

  // bits halfword pointer: word (bq*32+tl)*65 + hf*32 + (lane>>1), half lane&1
  unsigned short* bitsw = reinterpret_cast<unsigned short*>(smem) +
      ((bq * TC_) * 65 + hf * 32 + (lane >> 1)) * 2 + (lane & 1);
  const unsigned char* bytes = reinterpret_cast<const unsigned char*>(smem);

  for (int ch = 0; ch < NCH; ++ch) {
    // ---- phase 1: LIF for TC_ steps; descending-i addc bit collect ----
    for (int tl = 0; tl < TC_; ++tl) {
      unsigned W = 0;
#pragma unroll
      for (int i = 15; i >= 0; --i) {
        float m = fmaf(0.95f, mem1[i], c1v[i]);
        m = m - spk[i];
        mem1[i] = m;
        const bool c = m > 1.0f;
        W = W + W + (c ? 1u : 0u);
        spk[i] = c ? 1.0f : 0.0f;
      }
      bitsw[tl * 130] = (unsigned short)W;
    }
    __syncthreads();  // B1: bits ready (also fences comb vs prev P4)

    // ---- phase 2: MFMA partials over this wave's K-chunk, 4 batches ----
    for (int b = 0; b < GB_; ++b) {
#pragma unroll
      for (int tb = 0; tb < 2; ++tb) {
        f32x4 acc = {0.0f, 0.0f, 0.0f, 0.0f};
#pragma unroll
        for (int kbl = 0; kbl < 8; ++kbl) {
          const int kb = w * 8 + kbl;
          const unsigned byt =
              bytes[(b * 2080 + tb * 1040 + n15 * 65 + kb) * 4 + g];
          const uint2 lo2 = lut[byt & 15u];
          const uint2 hi2 = lut[byt >> 4];
          const u32x4 A = {lo2.x, lo2.y, hi2.x, hi2.y};
          const short8 af = __builtin_bit_cast(short8, A);
          acc = __builtin_amdgcn_mfma_f32_16x16x32_bf16(
              af, __builtin_bit_cast(short8, bhi[kbl]), acc, 0, 0, 0);
          acc = __builtin_amdgcn_mfma_f32_16x16x32_bf16(
              af, __builtin_bit_cast(short8, blo[kbl]), acc, 0, 0, 0);
        }
        if (n15 < NO_)
          *reinterpret_cast<f32x4*>(
              &comb[w * 1280 + b * 320 + tb * 160 + g * 40 + n15 * 4]) = acc;
      }
    }
    __syncthreads();  // B2: comb ready; bits dead

    // ---- phase 3+4 merged: direct 8-way comb sum + mem2 scan ----
    if (hf == 0 && lane < NO_) {
      const float* cbase = comb + bq * 320 + lane * 4;
#pragma unroll
      for (int tl = 0; tl < TC_; ++tl) {
        const int off = (tl >> 4) * 160 + ((tl & 15) >> 2) * 40 + (tl & 3);
        float s = 0.0f;
#pragma unroll
        for (int ww = 0; ww < 8; ++ww) s += cbase[ww * 1280 + off];
        const float cur2 = s + b2v;
        float m = fmaf(0.95f, mem2, cur2);
        m = m - spk2;
        mem2 = m;
        spk2 = (m > 1.0f) ? 1.0f : 0.0f;
        const int t = ch * TC_ + tl;
        srec[(size_t)t * (B_ * NO_)] = spk2;
        mrec[(size_t)t * (B_ * NO_)] = m;
      }
    }
    // no barrier: next P1 writes bits (dead since B2); comb overwrite is
    // fenced by the next B1; comb reads complete before this wave's B1.
  }
}

// ---------------------------------------------------------------------------
extern "C" void kernel_launch(void* const* d_in, const int* in_sizes, int n_in,
                              void* d_out, int out_size, void* d_ws, size_t ws_size,
                              hipStream_t stream) {
  const float* x  = (const float*)d_in[0];
  const float* w1 = (const float*)d_in[1];
  const float* b1 = (const float*)d_in[2];
  const float* w2 = (const float*)d_in[3];
  const float* b2 = (const float*)d_in[4];
  float* out = (float*)d_out;
  float* cur1 = (float*)d_ws;

  float* spk2_rec = out;
  float* mem2_rec = out + (size_t)T_ * B_ * NO_;

  (void)hipFuncSetAttribute(reinterpret_cast<const void*>(snn_loop),
                            hipFuncAttributeMaxDynamicSharedMemorySize,
                            SMEM_BYTES);

  dim3 g1(NH_ / 128, B_ / 128);
  gemm_cur1<<<g1, 512, 0, stream>>>(x, w1, b1, cur1);
  snn_loop<<<NBLK, 512, SMEM_BYTES, stream>>>(cur1, w2, b2, spk2_rec, mem2_rec);
}

// Round 14
// 185.749 us; speedup vs baseline: 1.0928x; 1.0928x over previous
//
#include <hip/hip_runtime.h>
#include <hip/hip_bf16.h>

// SNN: B=2048, NI=1024, NH=2048, NO=10, T=128, BETA=0.95, THR=1.0
// K1: cur1 = x @ w1^T + b1 via bf16x3 MFMA (frozen).
// K2: chunked LIF + time-as-M MFMA, GB=8 (r10 base).
// r14: (1) 256-entry byte->A-frag LUT at LDS 0: P2 kbl iter = u8 read + shl
//      + ds_read_b128 direct into MFMA A operand (was u8 + 2 nibble-LUT b64
//      + 4-mov assemble). (2) P1 fold reset: cc = spike ? c1-1 : c1 carried
//      across steps -> 4 inst/neuron-step. (3) merged P3/4 (no stag).

#define B_   2048
#define NI_  1024
#define NH_  2048
#define NO_  10
#define T_   128
#define GB_  8
#define NBLK (B_ / GB_)   // 256 blocks = 1/CU
#define TC_  32
#define NCH  (T_ / TC_)

typedef __attribute__((ext_vector_type(8))) short short8;
typedef __attribute__((ext_vector_type(4))) float f32x4;
typedef __attribute__((ext_vector_type(4))) unsigned int u32x4;

// bf16 round-to-nearest-even of an f32, low 16 bits.
__device__ __forceinline__ unsigned int bf16_rne(float f) {
  unsigned int u = __float_as_uint(f);
  return (u + 0x7FFFu + ((u >> 16) & 1u)) >> 16;
}

// ---------------- Kernel 1: cur1 = x @ w1^T + b1 (bf16x3 MFMA) --------------
#define G_ASTRIDE 144
#define G_AOFF    0
#define G_BOFF    (128 * G_ASTRIDE)
#define G_SMEM    (2 * 128 * G_ASTRIDE)

__global__ __launch_bounds__(512, 2) void gemm_cur1(
    const float* __restrict__ x, const float* __restrict__ w1,
    const float* __restrict__ b1, float* __restrict__ cur1) {
  __shared__ __align__(16) char smem[G_SMEM];
  const int tid = threadIdx.x;
  const int lane = tid & 63;
  const int wv = tid >> 6;
  const int wm = wv >> 2;
  const int wn = wv & 3;
  const int n15 = lane & 15;
  const int g = lane >> 4;
  const int brow = blockIdx.y * 128;
  const int bcol = blockIdx.x * 128;

  const int r_st = tid >> 3;
  const int kq = tid & 7;

  f32x4 acc[4][2];
#pragma unroll
  for (int tm = 0; tm < 4; ++tm)
#pragma unroll
    for (int tn = 0; tn < 2; ++tn) acc[tm][tn] = f32x4{0, 0, 0, 0};

  for (int kt = 0; kt < NI_; kt += 32) {
#pragma unroll
    for (int p = 0; p < 2; ++p) {
      const int r = r_st + p * 64;
      const float4 va = *reinterpret_cast<const float4*>(
          &x[(size_t)(brow + r) * NI_ + kt + kq * 4]);
      const float4 vb = *reinterpret_cast<const float4*>(
          &w1[(size_t)(bcol + r) * NI_ + kt + kq * 4]);
      const float fa[4] = {va.x, va.y, va.z, va.w};
      const float fb[4] = {vb.x, vb.y, vb.z, vb.w};
      unsigned ha[4], la[4], hb[4], lb[4];
#pragma unroll
      for (int c = 0; c < 4; ++c) {
        ha[c] = bf16_rne(fa[c]);
        la[c] = bf16_rne(fa[c] - __uint_as_float(ha[c] << 16));
        hb[c] = bf16_rne(fb[c]);
        lb[c] = bf16_rne(fb[c] - __uint_as_float(hb[c] << 16));
      }
      char* arow = smem + G_AOFF + r * G_ASTRIDE;
      char* brw  = smem + G_BOFF + r * G_ASTRIDE;
      *reinterpret_cast<uint2*>(arow + kq * 8) =
          uint2{ha[0] | (ha[1] << 16), ha[2] | (ha[3] << 16)};
      *reinterpret_cast<uint2*>(arow + 64 + kq * 8) =
          uint2{la[0] | (la[1] << 16), la[2] | (la[3] << 16)};
      *reinterpret_cast<uint2*>(brw + kq * 8) =
          uint2{hb[0] | (hb[1] << 16), hb[2] | (hb[3] << 16)};
      *reinterpret_cast<uint2*>(brw + 64 + kq * 8) =
          uint2{lb[0] | (lb[1] << 16), lb[2] | (lb[3] << 16)};
    }
    __syncthreads();

    short8 ah[4], al[4], bh2[2], bl2[2];
#pragma unroll
    for (int tm = 0; tm < 4; ++tm) {
      const char* p = smem + G_AOFF + (wm * 64 + tm * 16 + n15) * G_ASTRIDE;
      ah[tm] = *reinterpret_cast<const short8*>(p + g * 16);
      al[tm] = *reinterpret_cast<const short8*>(p + 64 + g * 16);
    }
#pragma unroll
    for (int tn = 0; tn < 2; ++tn) {
      const char* p = smem + G_BOFF + (wn * 32 + tn * 16 + n15) * G_ASTRIDE;
      bh2[tn] = *reinterpret_cast<const short8*>(p + g * 16);
      bl2[tn] = *reinterpret_cast<const short8*>(p + 64 + g * 16);
    }
#pragma unroll
    for (int tm = 0; tm < 4; ++tm)
#pragma unroll
      for (int tn = 0; tn < 2; ++tn) {
        acc[tm][tn] = __builtin_amdgcn_mfma_f32_16x16x32_bf16(
            ah[tm], bh2[tn], acc[tm][tn], 0, 0, 0);
        acc[tm][tn] = __builtin_amdgcn_mfma_f32_16x16x32_bf16(
            ah[tm], bl2[tn], acc[tm][tn], 0, 0, 0);
        acc[tm][tn] = __builtin_amdgcn_mfma_f32_16x16x32_bf16(
            al[tm], bh2[tn], acc[tm][tn], 0, 0, 0);
      }
    __syncthreads();
  }

#pragma unroll
  for (int tn = 0; tn < 2; ++tn) {
    const int col = bcol + wn * 32 + tn * 16 + n15;
    const float bias = b1[col];
#pragma unroll
    for (int tm = 0; tm < 4; ++tm) {
      const int rowb = brow + wm * 64 + tm * 16 + g * 4;
#pragma unroll
      for (int r = 0; r < 4; ++r)
        cur1[(size_t)(rowb + r) * NH_ + col] = acc[tm][tn][r] + bias;
    }
  }
}

// ---------------- Kernel 2: chunked LIF + time-as-M MFMA (GB=8) -------------
// LDS map (bytes):
//   lut  u32x4[256]  byte -> 8 bf16 A-frag      at 0       (4096)
//   bits u32[8 b][32 tl][65]                    at 4096    (66560)
//   comb f32[8 w][8 b][2 tb][4 g][10 n][4 r]    at 70656   (81920)
#define LUT_OFF  0
#define BITS_OFF 4096
#define COMB_OFF 70656
#define SMEM_BYTES 152576

__global__ __launch_bounds__(512, 2) void snn_loop(
    const float* __restrict__ cur1, const float* __restrict__ w2,
    const float* __restrict__ b2, float* __restrict__ spk2_rec,
    float* __restrict__ mem2_rec) {
  extern __shared__ char smem[];
  unsigned* bits = reinterpret_cast<unsigned*>(smem + BITS_OFF);
  float* comb = reinterpret_cast<float*>(smem + COMB_OFF);
  const int tid = threadIdx.x;
  const int lane = tid & 63;
  const int w = tid >> 6;               // wave id = local batch id
  const int bbase = blockIdx.x * GB_;
  const int bb = bbase + w;

  // ---- byte->A-frag LUT: entry b, word q = bf16 pair for bits 2q,2q+1 ----
  if (tid < 256) {
    u32x4 e;
#pragma unroll
    for (int q = 0; q < 4; ++q)
      e[q] = ((tid >> (2 * q)) & 1 ? 0x3F80u : 0u) |
             ((tid >> (2 * q + 1)) & 1 ? 0x3F800000u : 0u);
    *reinterpret_cast<u32x4*>(smem + LUT_OFF + tid * 16) = e;
  }

  // ---- layer-1 state: 32 contiguous h per lane (h = lane*32 + i) ----
  // cc[i] carries (c1 - prev_spike): fold of the reset subtraction.
  float mem1[32], c1v[32], c1m[32], cc[32];
  {
    const float* base = cur1 + (size_t)bb * NH_ + lane * 32;
#pragma unroll
    for (int q = 0; q < 8; ++q) {
      const float4 v = *reinterpret_cast<const float4*>(base + q * 4);
      c1v[q * 4 + 0] = v.x; c1v[q * 4 + 1] = v.y;
      c1v[q * 4 + 2] = v.z; c1v[q * 4 + 3] = v.w;
    }
#pragma unroll
    for (int i = 0; i < 32; ++i) {
      mem1[i] = 0.0f;
      c1m[i] = c1v[i] - 1.0f;
      cc[i] = c1v[i];
    }
  }

  // ---- w2 B-fragments in registers (hi/lo split) — verified ----
  u32x4 bhi[8], blo[8];
  {
    const int o = lane & 15;
    const int koff = (lane >> 4) * 8;
#pragma unroll
    for (int kbl = 0; kbl < 8; ++kbl) {
      const int kb = w * 8 + kbl;
      unsigned int hw[4], lw[4];
#pragma unroll
      for (int p = 0; p < 4; ++p) {
        unsigned int h0 = 0, h1 = 0, l0 = 0, l1 = 0;
        if (o < NO_) {
          const int k = kb * 32 + koff + p * 2;
          const float f0 = w2[(size_t)o * NH_ + k];
          const float f1 = w2[(size_t)o * NH_ + k + 1];
          h0 = bf16_rne(f0);
          h1 = bf16_rne(f1);
          l0 = bf16_rne(f0 - __uint_as_float(h0 << 16));
          l1 = bf16_rne(f1 - __uint_as_float(h1 << 16));
        }
        hw[p] = h0 | (h1 << 16);
        lw[p] = l0 | (l1 << 16);
      }
      bhi[kbl] = u32x4{hw[0], hw[1], hw[2], hw[3]};
      blo[kbl] = u32x4{lw[0], lw[1], lw[2], lw[3]};
    }
  }

  // ---- layer-2 state: lanes < NO_ of wave w own (batch bb, output o) ----
  float mem2 = 0.0f, spk2 = 0.0f, b2v = 0.0f;
  float *srec = nullptr, *mrec = nullptr;
  if (lane < NO_) {
    b2v = b2[lane];
    srec = spk2_rec + (size_t)bb * NO_ + lane;
    mrec = mem2_rec + (size_t)bb * NO_ + lane;
  }

  const int n15 = lane & 15;
  const int g = lane >> 4;

  unsigned* bitsrow = bits + w * 2080 + lane;
  // P2 per-lane byte base: byte g of word kb (kb = w*8+kbl) in row (b,tb,n15)
  const int base_bg = BITS_OFF + n15 * 260 + w * 32 + g;
  const unsigned char* bytes = reinterpret_cast<const unsigned char*>(smem);

  for (int ch = 0; ch < NCH; ++ch) {
    // ---- phase 1: LIF; 4 inst/neuron-step (fma, cmp, addc, cndmask) ----
    for (int tl = 0; tl < TC_; ++tl) {
      unsigned W = 0;
#pragma unroll
      for (int i = 31; i >= 0; --i) {
        const float m = fmaf(0.95f, mem1[i], cc[i]);
        mem1[i] = m;
        const bool c = m > 1.0f;
        W = W + W + (c ? 1u : 0u);
        cc[i] = c ? c1m[i] : c1v[i];
      }
      bitsrow[tl * 65] = W;
    }
    __syncthreads();  // B1: bits ready; prev P3/4 comb reads fenced

    // ---- phase 2: MFMA partials; byte-LUT -> A-frag direct ----
    for (int b = 0; b < GB_; ++b) {
#pragma unroll
      for (int tb = 0; tb < 2; ++tb) {
        const int rbase = base_bg + b * 8320 + tb * 4160;
        f32x4 acc = {0.0f, 0.0f, 0.0f, 0.0f};
#pragma unroll
        for (int kbl = 0; kbl < 8; ++kbl) {
          const unsigned byt = bytes[rbase + kbl * 4];
          const short8 af = *reinterpret_cast<const short8*>(
              smem + LUT_OFF + (byt << 4));
          acc = __builtin_amdgcn_mfma_f32_16x16x32_bf16(
              af, __builtin_bit_cast(short8, bhi[kbl]), acc, 0, 0, 0);
          acc = __builtin_amdgcn_mfma_f32_16x16x32_bf16(
              af, __builtin_bit_cast(short8, blo[kbl]), acc, 0, 0, 0);
        }
        if (n15 < NO_)
          *reinterpret_cast<f32x4*>(
              &comb[w * 2560 + b * 320 + tb * 160 + g * 40 + n15 * 4]) = acc;
      }
    }
    __syncthreads();  // B2: comb ready; bits dead

    // ---- phase 3+4 merged: 8-way comb sum + mem2 scan (own batch) ----
    if (lane < NO_) {
      const float* cbase = comb + w * 320 + lane * 4;
#pragma unroll
      for (int tl = 0; tl < TC_; ++tl) {
        const int off = (tl >> 4) * 160 + ((tl & 15) >> 2) * 40 + (tl & 3);
        float s = 0.0f;
#pragma unroll
        for (int ww = 0; ww < 8; ++ww) s += cbase[ww * 2560 + off];
        const float cur2 = s + b2v;
        float m = fmaf(0.95f, mem2, cur2);
        m = m - spk2;
        mem2 = m;
        spk2 = (m > 1.0f) ? 1.0f : 0.0f;
        const int t = ch * TC_ + tl;
        srec[(size_t)t * (B_ * NO_)] = spk2;
        mrec[(size_t)t * (B_ * NO_)] = m;
      }
    }
    // no barrier: next P1 writes bits (dead since B2); comb overwrite is
    // fenced by the next B1; comb reads complete before this wave's B1.
  }
}

// ---------------------------------------------------------------------------
extern "C" void kernel_launch(void* const* d_in, const int* in_sizes, int n_in,
                              void* d_out, int out_size, void* d_ws, size_t ws_size,
                              hipStream_t stream) {
  const float* x  = (const float*)d_in[0];
  const float* w1 = (const float*)d_in[1];
  const float* b1 = (const float*)d_in[2];
  const float* w2 = (const float*)d_in[3];
  const float* b2 = (const float*)d_in[4];
  float* out = (float*)d_out;
  float* cur1 = (float*)d_ws;

  float* spk2_rec = out;
  float* mem2_rec = out + (size_t)T_ * B_ * NO_;

  (void)hipFuncSetAttribute(reinterpret_cast<const void*>(snn_loop),
                            hipFuncAttributeMaxDynamicSharedMemorySize,
                            SMEM_BYTES);

  dim3 g1(NH_ / 128, B_ / 128);
  gemm_cur1<<<g1, 512, 0, stream>>>(x, w1, b1, cur1);
  snn_loop<<<NBLK, 512, SMEM_BYTES, stream>>>(cur1, w2, b2, spk2_rec, mem2_rec);
}

// Round 15
// 181.027 us; speedup vs baseline: 1.1213x; 1.0261x over previous
//
#include <hip/hip_runtime.h>
#include <hip/hip_bf16.h>

// SNN: B=2048, NI=1024, NH=2048, NO=10, T=128, BETA=0.95, THR=1.0
// K1: cur1 = x @ w1^T + b1 via bf16x3 MFMA (frozen).
// K2: r15 software-pipelined: TC=16, double-buffered bits+comb; each bundle
//     interleaves P3/4(ch-1) + P2(ch) + P1(ch+1); one barrier per bundle.
//     Nibble LUT (16x2 words = 32 banks, conflict-free by construction).

#define B_   2048
#define NI_  1024
#define NH_  2048
#define NO_  10
#define T_   128
#define GB_  8
#define NBLK (B_ / GB_)   // 256 blocks = 1/CU
#define TC_  16
#define NCH  (T_ / TC_)   // 8 chunks

typedef __attribute__((ext_vector_type(8))) short short8;
typedef __attribute__((ext_vector_type(4))) float f32x4;
typedef __attribute__((ext_vector_type(4))) unsigned int u32x4;

// bf16 round-to-nearest-even of an f32, low 16 bits.
__device__ __forceinline__ unsigned int bf16_rne(float f) {
  unsigned int u = __float_as_uint(f);
  return (u + 0x7FFFu + ((u >> 16) & 1u)) >> 16;
}

// ---------------- Kernel 1: cur1 = x @ w1^T + b1 (bf16x3 MFMA) --------------
#define G_ASTRIDE 144
#define G_AOFF    0
#define G_BOFF    (128 * G_ASTRIDE)
#define G_SMEM    (2 * 128 * G_ASTRIDE)

__global__ __launch_bounds__(512, 2) void gemm_cur1(
    const float* __restrict__ x, const float* __restrict__ w1,
    const float* __restrict__ b1, float* __restrict__ cur1) {
  __shared__ __align__(16) char smem[G_SMEM];
  const int tid = threadIdx.x;
  const int lane = tid & 63;
  const int wv = tid >> 6;
  const int wm = wv >> 2;
  const int wn = wv & 3;
  const int n15 = lane & 15;
  const int g = lane >> 4;
  const int brow = blockIdx.y * 128;
  const int bcol = blockIdx.x * 128;

  const int r_st = tid >> 3;
  const int kq = tid & 7;

  f32x4 acc[4][2];
#pragma unroll
  for (int tm = 0; tm < 4; ++tm)
#pragma unroll
    for (int tn = 0; tn < 2; ++tn) acc[tm][tn] = f32x4{0, 0, 0, 0};

  for (int kt = 0; kt < NI_; kt += 32) {
#pragma unroll
    for (int p = 0; p < 2; ++p) {
      const int r = r_st + p * 64;
      const float4 va = *reinterpret_cast<const float4*>(
          &x[(size_t)(brow + r) * NI_ + kt + kq * 4]);
      const float4 vb = *reinterpret_cast<const float4*>(
          &w1[(size_t)(bcol + r) * NI_ + kt + kq * 4]);
      const float fa[4] = {va.x, va.y, va.z, va.w};
      const float fb[4] = {vb.x, vb.y, vb.z, vb.w};
      unsigned ha[4], la[4], hb[4], lb[4];
#pragma unroll
      for (int c = 0; c < 4; ++c) {
        ha[c] = bf16_rne(fa[c]);
        la[c] = bf16_rne(fa[c] - __uint_as_float(ha[c] << 16));
        hb[c] = bf16_rne(fb[c]);
        lb[c] = bf16_rne(fb[c] - __uint_as_float(hb[c] << 16));
      }
      char* arow = smem + G_AOFF + r * G_ASTRIDE;
      char* brw  = smem + G_BOFF + r * G_ASTRIDE;
      *reinterpret_cast<uint2*>(arow + kq * 8) =
          uint2{ha[0] | (ha[1] << 16), ha[2] | (ha[3] << 16)};
      *reinterpret_cast<uint2*>(arow + 64 + kq * 8) =
          uint2{la[0] | (la[1] << 16), la[2] | (la[3] << 16)};
      *reinterpret_cast<uint2*>(brw + kq * 8) =
          uint2{hb[0] | (hb[1] << 16), hb[2] | (hb[3] << 16)};
      *reinterpret_cast<uint2*>(brw + 64 + kq * 8) =
          uint2{lb[0] | (lb[1] << 16), lb[2] | (lb[3] << 16)};
    }
    __syncthreads();

    short8 ah[4], al[4], bh2[2], bl2[2];
#pragma unroll
    for (int tm = 0; tm < 4; ++tm) {
      const char* p = smem + G_AOFF + (wm * 64 + tm * 16 + n15) * G_ASTRIDE;
      ah[tm] = *reinterpret_cast<const short8*>(p + g * 16);
      al[tm] = *reinterpret_cast<const short8*>(p + 64 + g * 16);
    }
#pragma unroll
    for (int tn = 0; tn < 2; ++tn) {
      const char* p = smem + G_BOFF + (wn * 32 + tn * 16 + n15) * G_ASTRIDE;
      bh2[tn] = *reinterpret_cast<const short8*>(p + g * 16);
      bl2[tn] = *reinterpret_cast<const short8*>(p + 64 + g * 16);
    }
#pragma unroll
    for (int tm = 0; tm < 4; ++tm)
#pragma unroll
      for (int tn = 0; tn < 2; ++tn) {
        acc[tm][tn] = __builtin_amdgcn_mfma_f32_16x16x32_bf16(
            ah[tm], bh2[tn], acc[tm][tn], 0, 0, 0);
        acc[tm][tn] = __builtin_amdgcn_mfma_f32_16x16x32_bf16(
            ah[tm], bl2[tn], acc[tm][tn], 0, 0, 0);
        acc[tm][tn] = __builtin_amdgcn_mfma_f32_16x16x32_bf16(
            al[tm], bh2[tn], acc[tm][tn], 0, 0, 0);
      }
    __syncthreads();
  }

#pragma unroll
  for (int tn = 0; tn < 2; ++tn) {
    const int col = bcol + wn * 32 + tn * 16 + n15;
    const float bias = b1[col];
#pragma unroll
    for (int tm = 0; tm < 4; ++tm) {
      const int rowb = brow + wm * 64 + tm * 16 + g * 4;
#pragma unroll
      for (int r = 0; r < 4; ++r)
        cur1[(size_t)(rowb + r) * NH_ + col] = acc[tm][tn][r] + bias;
    }
  }
}

// ---------------- Kernel 2: pipelined LIF + time-as-M MFMA ------------------
// LDS map (bytes):
//   lut  uint2[16]                      at 0       (128; 32 words = 32 banks)
//   bits u32[2 par][8 b][16 tl][65]     at 128     (2 x 33280)
//   comb f32[2 par][8 w][8 b][4 g][40]  at 66688   (2 x 40960)
#define LUT_OFF  0
#define BITS_OFF 128
#define BITS_PAR 8320    // words per parity
#define COMB_OFF 66688
#define COMB_PAR 10240   // floats per parity
#define SMEM_BYTES 148608

__global__ __launch_bounds__(512, 2) void snn_loop(
    const float* __restrict__ cur1, const float* __restrict__ w2,
    const float* __restrict__ b2, float* __restrict__ spk2_rec,
    float* __restrict__ mem2_rec) {
  extern __shared__ char smem[];
  uint2* lutw = reinterpret_cast<uint2*>(smem + LUT_OFF);
  const uint2* lut = lutw;
  unsigned* bits = reinterpret_cast<unsigned*>(smem + BITS_OFF);
  float* comb = reinterpret_cast<float*>(smem + COMB_OFF);
  const int tid = threadIdx.x;
  const int lane = tid & 63;
  const int w = tid >> 6;               // wave id = local batch id
  const int bbase = blockIdx.x * GB_;
  const int bb = bbase + w;

  if (tid < 16) {
    lutw[tid] = uint2{(tid & 1 ? 0x3F80u : 0u) | (tid & 2 ? 0x3F800000u : 0u),
                      (tid & 4 ? 0x3F80u : 0u) | (tid & 8 ? 0x3F800000u : 0u)};
  }

  // ---- layer-1 state: 32 contiguous h per lane; folded reset (r14) ----
  float mem1[32], c1v[32], c1m[32], cc[32];
  {
    const float* base = cur1 + (size_t)bb * NH_ + lane * 32;
#pragma unroll
    for (int q = 0; q < 8; ++q) {
      const float4 v = *reinterpret_cast<const float4*>(base + q * 4);
      c1v[q * 4 + 0] = v.x; c1v[q * 4 + 1] = v.y;
      c1v[q * 4 + 2] = v.z; c1v[q * 4 + 3] = v.w;
    }
#pragma unroll
    for (int i = 0; i < 32; ++i) {
      mem1[i] = 0.0f;
      c1m[i] = c1v[i] - 1.0f;
      cc[i] = c1v[i];
    }
  }

  // ---- w2 B-fragments in registers (hi/lo split) — verified ----
  u32x4 bhi[8], blo[8];
  {
    const int o = lane & 15;
    const int koff = (lane >> 4) * 8;
#pragma unroll
    for (int kbl = 0; kbl < 8; ++kbl) {
      const int kb = w * 8 + kbl;
      unsigned int hw[4], lw[4];
#pragma unroll
      for (int p = 0; p < 4; ++p) {
        unsigned int h0 = 0, h1 = 0, l0 = 0, l1 = 0;
        if (o < NO_) {
          const int k = kb * 32 + koff + p * 2;
          const float f0 = w2[(size_t)o * NH_ + k];
          const float f1 = w2[(size_t)o * NH_ + k + 1];
          h0 = bf16_rne(f0);
          h1 = bf16_rne(f1);
          l0 = bf16_rne(f0 - __uint_as_float(h0 << 16));
          l1 = bf16_rne(f1 - __uint_as_float(h1 << 16));
        }
        hw[p] = h0 | (h1 << 16);
        lw[p] = l0 | (l1 << 16);
      }
      bhi[kbl] = u32x4{hw[0], hw[1], hw[2], hw[3]};
      blo[kbl] = u32x4{lw[0], lw[1], lw[2], lw[3]};
    }
  }

  // ---- layer-2 state: lanes < NO_ of wave w own (batch bb, output o) ----
  float mem2 = 0.0f, spk2 = 0.0f, b2v = 0.0f;
  float *srec = nullptr, *mrec = nullptr;
  if (lane < NO_) {
    b2v = b2[lane];
    srec = spk2_rec + (size_t)bb * NO_ + lane;
    mrec = mem2_rec + (size_t)bb * NO_ + lane;
  }

  const int n15 = lane & 15;
  const int g = lane >> 4;
  const unsigned char* bytes = reinterpret_cast<const unsigned char*>(smem);

  // ---- P1 macro: one LIF step tl into parity-p bits ----
  auto P1_STEP = [&](unsigned* bitsP, int tl) {
    unsigned W = 0;
#pragma unroll
    for (int i = 31; i >= 0; --i) {
      const float m = fmaf(0.95f, mem1[i], cc[i]);
      mem1[i] = m;
      const bool c = m > 1.0f;
      W = W + W + (c ? 1u : 0u);
      cc[i] = c ? c1m[i] : c1v[i];
    }
    bitsP[(w * TC_ + tl) * 65 + lane] = W;
  };

  // ---- prologue: P1(chunk 0) -> parity 0 ----
  for (int tl = 0; tl < TC_; ++tl) P1_STEP(bits, tl);
  __syncthreads();

  for (int ch = 0; ch < NCH; ++ch) {
    const int cur = ch & 1;
    unsigned* bitsN = bits + (cur ^ 1) * BITS_PAR;
    float* combC = comb + cur * COMB_PAR;
    const float* combV = comb + (cur ^ 1) * COMB_PAR;  // parity of ch-1
    const int bbyte = BITS_OFF + cur * (BITS_PAR * 4);

    // ---- (a) P3/4 for chunk ch-1 (independent of (b)) ----
    if (ch > 0 && lane < NO_) {
      const float* cbase = combV + w * 160 + lane * 4;
#pragma unroll
      for (int tl = 0; tl < TC_; ++tl) {
        const int off = (tl >> 2) * 40 + (tl & 3);
        float s = 0.0f;
#pragma unroll
        for (int ww = 0; ww < 8; ++ww) s += cbase[ww * 1280 + off];
        const float cur2 = s + b2v;
        float m = fmaf(0.95f, mem2, cur2);
        m = m - spk2;
        mem2 = m;
        spk2 = (m > 1.0f) ? 1.0f : 0.0f;
        const int t = (ch - 1) * TC_ + tl;
        srec[(size_t)t * (B_ * NO_)] = spk2;
        mrec[(size_t)t * (B_ * NO_)] = m;
      }
    }

    // ---- (b) fused P2(ch) + P1(ch+1): 8 b-iters x {16 MFMA | 2 LIF steps} --
#pragma unroll
    for (int b = 0; b < GB_; ++b) {
      const int rbase = bbyte + ((b * TC_ + n15) * 65 + w * 8) * 4 + g;
      f32x4 acc = {0.0f, 0.0f, 0.0f, 0.0f};
#pragma unroll
      for (int kbl = 0; kbl < 8; ++kbl) {
        const unsigned byt = bytes[rbase + kbl * 4];
        const uint2 lo2 = lut[byt & 15u];
        const uint2 hi2 = lut[byt >> 4];
        const u32x4 A = {lo2.x, lo2.y, hi2.x, hi2.y};
        const short8 af = __builtin_bit_cast(short8, A);
        acc = __builtin_amdgcn_mfma_f32_16x16x32_bf16(
            af, __builtin_bit_cast(short8, bhi[kbl]), acc, 0, 0, 0);
        acc = __builtin_amdgcn_mfma_f32_16x16x32_bf16(
            af, __builtin_bit_cast(short8, blo[kbl]), acc, 0, 0, 0);
      }
      if (n15 < NO_)
        *reinterpret_cast<f32x4*>(
            &combC[w * 1280 + b * 160 + g * 40 + n15 * 4]) = acc;
      if (ch < NCH - 1) {
        P1_STEP(bitsN, 2 * b);
        P1_STEP(bitsN, 2 * b + 1);
      }
    }

    __syncthreads();
    // fences: bits(nxt) ready for P2(ch+1); comb(cur) ready for P3/4(ch);
    // all reads of bits(cur) done before P1(ch+2) overwrites it; all reads
    // of comb(ch-1 parity) done before P2(ch+1) overwrites it.
  }

  // ---- epilogue: P3/4 for last chunk (parity (NCH-1)&1) ----
  if (lane < NO_) {
    const float* cbase = comb + ((NCH - 1) & 1) * COMB_PAR + w * 160 + lane * 4;
#pragma unroll
    for (int tl = 0; tl < TC_; ++tl) {
      const int off = (tl >> 2) * 40 + (tl & 3);
      float s = 0.0f;
#pragma unroll
      for (int ww = 0; ww < 8; ++ww) s += cbase[ww * 1280 + off];
      const float cur2 = s + b2v;
      float m = fmaf(0.95f, mem2, cur2);
      m = m - spk2;
      mem2 = m;
      spk2 = (m > 1.0f) ? 1.0f : 0.0f;
      const int t = (NCH - 1) * TC_ + tl;
      srec[(size_t)t * (B_ * NO_)] = spk2;
      mrec[(size_t)t * (B_ * NO_)] = m;
    }
  }
}

// ---------------------------------------------------------------------------
extern "C" void kernel_launch(void* const* d_in, const int* in_sizes, int n_in,
                              void* d_out, int out_size, void* d_ws, size_t ws_size,
                              hipStream_t stream) {
  const float* x  = (const float*)d_in[0];
  const float* w1 = (const float*)d_in[1];
  const float* b1 = (const float*)d_in[2];
  const float* w2 = (const float*)d_in[3];
  const float* b2 = (const float*)d_in[4];
  float* out = (float*)d_out;
  float* cur1 = (float*)d_ws;

  float* spk2_rec = out;
  float* mem2_rec = out + (size_t)T_ * B_ * NO_;

  (void)hipFuncSetAttribute(reinterpret_cast<const void*>(snn_loop),
                            hipFuncAttributeMaxDynamicSharedMemorySize,
                            SMEM_BYTES);

  dim3 g1(NH_ / 128, B_ / 128);
  gemm_cur1<<<g1, 512, 0, stream>>>(x, w1, b1, cur1);
  snn_loop<<<NBLK, 512, SMEM_BYTES, stream>>>(cur1, w2, b2, spk2_rec, mem2_rec);
}